// Round 2
// baseline (9811.255 us; speedup 1.0000x reference)
//
#include <hip/hip_runtime.h>
#include <math.h>

#define B_ 32
#define T_ 1024
#define D_ 1024
#define S_ 128
#define H_ 4096
#define M_ (B_*T_)          // 32768 rows
#define LN_EPS 1e-5f

// ---------------------------------------------------------------------------
// LayerNorm over last dim (D=1024). One block (256 thr) per row, float4 loads.
// ADD_INPUT=false: out = LN(x)*w+b        (stage A)
// ADD_INPUT=true : out = x + LN(x)*w+b    (stage G)
// ---------------------------------------------------------------------------
template<bool ADD_INPUT>
__global__ __launch_bounds__(256) void ln_kernel(const float* __restrict__ x,
                                                 const float* __restrict__ w,
                                                 const float* __restrict__ b,
                                                 float* __restrict__ out)
{
    const int row = blockIdx.x;
    const int tid = threadIdx.x;
    const float4* xr = (const float4*)(x + (size_t)row * D_);
    float4 v = xr[tid];

    float s  = v.x + v.y + v.z + v.w;
    float ss = v.x*v.x + v.y*v.y + v.z*v.z + v.w*v.w;
    #pragma unroll
    for (int off = 32; off; off >>= 1) {
        s  += __shfl_down(s,  off);
        ss += __shfl_down(ss, off);
    }
    __shared__ float redS[4], redS2[4];
    __shared__ float mu_s, rstd_s;
    const int wave = tid >> 6;
    if ((tid & 63) == 0) { redS[wave] = s; redS2[wave] = ss; }
    __syncthreads();
    if (tid == 0) {
        float s0 = redS[0]+redS[1]+redS[2]+redS[3];
        float s1 = redS2[0]+redS2[1]+redS2[2]+redS2[3];
        float mu = s0 * (1.0f / D_);
        float var = s1 * (1.0f / D_) - mu * mu;
        mu_s = mu;
        rstd_s = rsqrtf(var + LN_EPS);
    }
    __syncthreads();
    const float mu = mu_s, rstd = rstd_s;

    float4 wv = ((const float4*)w)[tid];
    float4 bv = ((const float4*)b)[tid];
    float4 o;
    o.x = (v.x - mu) * rstd * wv.x + bv.x;
    o.y = (v.y - mu) * rstd * wv.y + bv.y;
    o.z = (v.z - mu) * rstd * wv.z + bv.z;
    o.w = (v.w - mu) * rstd * wv.w + bv.w;
    if (ADD_INPUT) { o.x += v.x; o.y += v.y; o.z += v.z; o.w += v.w; }
    ((float4*)(out + (size_t)row * D_))[tid] = o;
}

// ---------------------------------------------------------------------------
// Generic fp32 NT GEMM: out[o][n] = sum_k A[arow(o)][k] * W[n][k]  (+ epilogue)
//   REMAP: arow = (o % r1) * r2 + o / r1   (else arow = o)
//   EPI: 0 none | 1 +bias | 2 gelu(.+bias) | 3 +resid[o][n]
// Block: (BM/TM)*(BN/TN) = 256 threads. M,N,K multiples of BM,BN,BK assumed.
// NOTE: `resid` and `out` may alias (stage D writes in place) -> no __restrict__.
// ---------------------------------------------------------------------------
__device__ __forceinline__ float gelu_exact(float v) {
    return 0.5f * v * (1.0f + erff(v * 0.70710678118654752f));
}

template<int BM,int BN,int BK,int TM,int TN,int EPI,bool REMAP>
__global__ __launch_bounds__(256) void gemm_nt(const float* __restrict__ A,
                                               const float* __restrict__ W,
                                               const float* __restrict__ bias,
                                               const float* resid,
                                               float* out,
                                               int N, int K, int r1, int r2)
{
    constexpr int NT = (BM/TM)*(BN/TN);   // 256
    __shared__ float As[BK][BM+4];
    __shared__ float Ws[BK][BN+4];

    const int tid = threadIdx.x;
    const int bn0 = blockIdx.x * BN;
    const int bm0 = blockIdx.y * BM;
    const int tx = tid % (BN/TN);
    const int ty = tid / (BN/TN);

    float acc[TM][TN];
    #pragma unroll
    for (int i = 0; i < TM; i++)
        #pragma unroll
        for (int j = 0; j < TN; j++) acc[i][j] = 0.f;

    for (int k0 = 0; k0 < K; k0 += BK) {
        // stage A tile (transposed into As[k][m])
        #pragma unroll
        for (int idx = tid; idx < (BM*BK)/4; idx += NT) {
            int c = idx & (BK/4 - 1);
            int r = idx / (BK/4);
            int orow = bm0 + r;
            int arow = REMAP ? (orow % r1) * r2 + orow / r1 : orow;
            float4 a = *(const float4*)(A + (size_t)arow * K + k0 + c*4);
            As[c*4+0][r] = a.x; As[c*4+1][r] = a.y;
            As[c*4+2][r] = a.z; As[c*4+3][r] = a.w;
        }
        // stage W tile
        #pragma unroll
        for (int idx = tid; idx < (BN*BK)/4; idx += NT) {
            int c = idx & (BK/4 - 1);
            int r = idx / (BK/4);
            float4 a = *(const float4*)(W + (size_t)(bn0 + r) * K + k0 + c*4);
            Ws[c*4+0][r] = a.x; Ws[c*4+1][r] = a.y;
            Ws[c*4+2][r] = a.z; Ws[c*4+3][r] = a.w;
        }
        __syncthreads();

        #pragma unroll
        for (int kk = 0; kk < BK; kk++) {
            float av[TM], bv[TN];
            #pragma unroll
            for (int i = 0; i < TM; i += 4) {
                float4 t4 = *(const float4*)&As[kk][ty*TM + i];
                av[i] = t4.x; av[i+1] = t4.y; av[i+2] = t4.z; av[i+3] = t4.w;
            }
            #pragma unroll
            for (int j = 0; j < TN; j += 4) {
                float4 t4 = *(const float4*)&Ws[kk][tx*TN + j];
                bv[j] = t4.x; bv[j+1] = t4.y; bv[j+2] = t4.z; bv[j+3] = t4.w;
            }
            #pragma unroll
            for (int i = 0; i < TM; i++)
                #pragma unroll
                for (int j = 0; j < TN; j++)
                    acc[i][j] = fmaf(av[i], bv[j], acc[i][j]);
        }
        __syncthreads();
    }

    // epilogue
    #pragma unroll
    for (int i = 0; i < TM; i++) {
        const int o = bm0 + ty*TM + i;
        float* orow = out + (size_t)o * N + bn0 + tx*TN;
        #pragma unroll
        for (int j = 0; j < TN; j += 4) {
            float4 r;
            r.x = acc[i][j+0]; r.y = acc[i][j+1]; r.z = acc[i][j+2]; r.w = acc[i][j+3];
            if (EPI == 1 || EPI == 2) {
                float4 bb = *(const float4*)(bias + bn0 + tx*TN + j);
                r.x += bb.x; r.y += bb.y; r.z += bb.z; r.w += bb.w;
            }
            if (EPI == 2) {
                r.x = gelu_exact(r.x); r.y = gelu_exact(r.y);
                r.z = gelu_exact(r.z); r.w = gelu_exact(r.w);
            }
            if (EPI == 3) {
                float4 rr;
                rr.x = resid[(size_t)o * N + bn0 + tx*TN + j + 0];
                rr.y = resid[(size_t)o * N + bn0 + tx*TN + j + 1];
                rr.z = resid[(size_t)o * N + bn0 + tx*TN + j + 2];
                rr.w = resid[(size_t)o * N + bn0 + tx*TN + j + 3];
                r.x += rr.x; r.y += rr.y; r.z += rr.z; r.w += rr.w;
            }
            *(float4*)(orow + j) = r;
        }
    }
}

// ---------------------------------------------------------------------------
// Sequential state scan. One block per batch b (32 blocks), 1024 threads.
// Weights (gate_w / state_flow rows) live in REGISTERS (32 floats/thread);
// h lives in LDS. Thread t: mv = t>>9 (0:gate,1:flow), s = (t>>2)&127,
// p = t&3 -> 32-wide k-slice; 2 shfl_xor to reduce the 4 partials.
// inj / h_all layout: [(t*B + b)*S + s]. inj MAY ALIAS h_all (in-place):
// each offset is read (into reg) before being overwritten by the same thread.
// ---------------------------------------------------------------------------
__global__ __launch_bounds__(1024) void scan_kernel(const float* inj,
                                                    const float* __restrict__ gate_w,
                                                    const float* __restrict__ gate_b,
                                                    const float* __restrict__ state_flow,
                                                    float* h_all)
{
    const int b = blockIdx.x;
    const int t = threadIdx.x;
    const int mv = t >> 9;
    const int s  = (t >> 2) & 127;
    const int p  = t & 3;
    const int k0 = p * 32;

    const float* Wrow = (mv ? state_flow : gate_w) + (size_t)s * S_ + k0;
    float w[32];
    #pragma unroll
    for (int i = 0; i < 32; i += 4) {
        float4 t4 = *(const float4*)(Wrow + i);
        w[i] = t4.x; w[i+1] = t4.y; w[i+2] = t4.z; w[i+3] = t4.w;
    }
    const float gbv = (t < S_) ? gate_b[t] : 0.f;

    __shared__ __align__(16) float h[S_];
    __shared__ float red[2][S_];
    if (t < S_) h[t] = 0.f;
    __syncthreads();

    const float* injb = inj   + (size_t)b * S_;
    float*       hab  = h_all + (size_t)b * S_;

    for (int step = 0; step < T_; step++) {
        float a0 = 0.f, a1 = 0.f, a2 = 0.f, a3 = 0.f;
        #pragma unroll
        for (int i = 0; i < 8; i++) {
            float4 hh = *(const float4*)&h[k0 + i*4];
            a0 = fmaf(w[i*4+0], hh.x, a0);
            a1 = fmaf(w[i*4+1], hh.y, a1);
            a2 = fmaf(w[i*4+2], hh.z, a2);
            a3 = fmaf(w[i*4+3], hh.w, a3);
        }
        float dot = (a0 + a1) + (a2 + a3);
        dot += __shfl_xor(dot, 1);
        dot += __shfl_xor(dot, 2);
        if (p == 0) red[mv][s] = dot;
        __syncthreads();
        if (t < S_) {
            const size_t off = (size_t)step * (B_ * S_) + t;
            const float injv = injb[off];          // read BEFORE in-place write
            float g  = 1.f / (1.f + expf(-(red[0][t] + gbv + injv)));
            float hn = (1.f - g) * h[t] + g * red[1][t];
            h[t] = hn;
            hab[off] = hn;
        }
        __syncthreads();
    }
}

// ---------------------------------------------------------------------------
extern "C" void kernel_launch(void* const* d_in, const int* in_sizes, int n_in,
                              void* d_out, int out_size, void* d_ws, size_t ws_size,
                              hipStream_t stream)
{
    const float* x          = (const float*)d_in[0];
    const float* ln1_w      = (const float*)d_in[1];
    const float* ln1_b      = (const float*)d_in[2];
    const float* state_flow = (const float*)d_in[3];
    const float* injection  = (const float*)d_in[4];
    const float* readout    = (const float*)d_in[5];
    const float* gate_w     = (const float*)d_in[6];
    const float* gate_b     = (const float*)d_in[7];
    const float* mlp_w1     = (const float*)d_in[8];
    const float* mlp_b1     = (const float*)d_in[9];
    const float* mlp_w2     = (const float*)d_in[10];
    const float* mlp_b2     = (const float*)d_in[11];
    const float* ln2_w      = (const float*)d_in[12];
    const float* ln2_b      = (const float*)d_in[13];
    float* out = (float*)d_out;
    float* ws  = (float*)d_ws;

    const size_t MD  = (size_t)M_ * D_;       // 33.55M floats
    const size_t TBS = (size_t)T_ * B_ * S_;  // 4.19M floats

    // Workspace layout (in-place reuse; ~185-218 MB):
    //   xb  [M,D]   : LN1 out -> (D, in place) post-state residual -> (F, in
    //                 place) MLP out; read by final LN2 kernel.
    //   inj [T,B,S] : injection GEMM out -> (scan, in place) h_all.
    //   hch [MC,H]  : MLP hidden chunk.
    float* xb  = ws;
    float* inj = xb + MD;
    float* hch = inj + TBS;

    // pick largest MLP row-chunk that fits the provided workspace
    const size_t avail = ws_size / sizeof(float);
    int MC = 4096;
    while (MC > 512 && MD + TBS + (size_t)MC * H_ > avail) MC >>= 1;

    // A: xb = LN1(x)
    ln_kernel<false><<<M_, 256, 0, stream>>>(x, ln1_w, ln1_b, xb);

    // B: inj[t*B+b][s] = sum_d xb[b*T+t][d] * injection[s][d]
    gemm_nt<64,64,16,4,4,0,true><<<dim3(S_/64, M_/64), 256, 0, stream>>>(
        xb, injection, nullptr, nullptr, inj, S_, D_, B_, T_);

    // C: sequential gated state scan, in place: inj -> h_all
    scan_kernel<<<B_, 1024, 0, stream>>>(inj, gate_w, gate_b, state_flow, inj);

    // D (in place): xb[b*T+t][d] = sum_s inj[t*B+b][s]*readout[d][s] + xb[b*T+t][d]
    gemm_nt<64,64,16,4,4,3,true><<<dim3(D_/64, M_/64), 256, 0, stream>>>(
        inj, readout, nullptr, xb, xb, D_, S_, T_, B_);

    // E/F: MLP, chunked over rows; F writes back into xb in place
    for (int c = 0; c < M_ / MC; c++) {
        gemm_nt<128,128,16,8,8,2,false><<<dim3(H_/128, MC/128), 256, 0, stream>>>(
            xb + (size_t)c*MC*D_, mlp_w1, mlp_b1, nullptr, hch, H_, D_, 0, 0);
        gemm_nt<128,128,16,8,8,1,false><<<dim3(D_/128, MC/128), 256, 0, stream>>>(
            hch, mlp_w2, mlp_b2, nullptr, xb + (size_t)c*MC*D_, D_, H_, 0, 0);
    }

    // G: out = xb + LN2(xb)
    ln_kernel<true><<<M_, 256, 0, stream>>>(xb, ln2_w, ln2_b, out);
}

// Round 3
// 3386.536 us; speedup vs baseline: 2.8971x; 2.8971x over previous
//
#include <hip/hip_runtime.h>
#include <math.h>

#define B_ 32
#define T_ 1024
#define D_ 1024
#define S_ 128
#define H_ 4096
#define M_ (B_*T_)          // 32768 rows
#define LN_EPS 1e-5f

typedef unsigned short u16;
typedef unsigned int   u32;
typedef short short8 __attribute__((ext_vector_type(8)));
typedef float f32x4  __attribute__((ext_vector_type(4)));

// bf16 round-to-nearest-even helpers (bit ops, no header type dependencies)
__device__ __forceinline__ u16 f2bf(float x) {
    u32 u = __float_as_uint(x);
    u += 0x7FFFu + ((u >> 16) & 1u);
    return (u16)(u >> 16);
}
__device__ __forceinline__ float bf2f(u16 h) {
    return __uint_as_float(((u32)h) << 16);
}

// ---------------------------------------------------------------------------
// LayerNorm over last dim (D=1024). One block (256 thr) per row, float4 loads.
// ---------------------------------------------------------------------------
template<bool ADD_INPUT>
__global__ __launch_bounds__(256) void ln_kernel(const float* __restrict__ x,
                                                 const float* __restrict__ w,
                                                 const float* __restrict__ b,
                                                 float* __restrict__ out)
{
    const int row = blockIdx.x;
    const int tid = threadIdx.x;
    const float4* xr = (const float4*)(x + (size_t)row * D_);
    float4 v = xr[tid];

    float s  = v.x + v.y + v.z + v.w;
    float ss = v.x*v.x + v.y*v.y + v.z*v.z + v.w*v.w;
    #pragma unroll
    for (int off = 32; off; off >>= 1) {
        s  += __shfl_down(s,  off);
        ss += __shfl_down(ss, off);
    }
    __shared__ float redS[4], redS2[4];
    __shared__ float mu_s, rstd_s;
    const int wave = tid >> 6;
    if ((tid & 63) == 0) { redS[wave] = s; redS2[wave] = ss; }
    __syncthreads();
    if (tid == 0) {
        float s0 = redS[0]+redS[1]+redS[2]+redS[3];
        float s1 = redS2[0]+redS2[1]+redS2[2]+redS2[3];
        float mu = s0 * (1.0f / D_);
        float var = s1 * (1.0f / D_) - mu * mu;
        mu_s = mu;
        rstd_s = rsqrtf(var + LN_EPS);
    }
    __syncthreads();
    const float mu = mu_s, rstd = rstd_s;

    float4 wv = ((const float4*)w)[tid];
    float4 bv = ((const float4*)b)[tid];
    float4 o;
    o.x = (v.x - mu) * rstd * wv.x + bv.x;
    o.y = (v.y - mu) * rstd * wv.y + bv.y;
    o.z = (v.z - mu) * rstd * wv.z + bv.z;
    o.w = (v.w - mu) * rstd * wv.w + bv.w;
    if (ADD_INPUT) { o.x += v.x; o.y += v.y; o.z += v.z; o.w += v.w; }
    ((float4*)(out + (size_t)row * D_))[tid] = o;
}

// ---------------------------------------------------------------------------
// fp32 NT GEMM (kept for the two small S=128 GEMMs: inj and readout).
//   REMAP: arow = (o % r1) * r2 + o / r1
//   EPI: 0 none | 3 +resid[o][n]  (resid/out may alias)
// ---------------------------------------------------------------------------
template<int BM,int BN,int BK,int TM,int TN,int EPI,bool REMAP>
__global__ __launch_bounds__(256) void gemm_nt(const float* __restrict__ A,
                                               const float* __restrict__ W,
                                               const float* resid,
                                               float* out,
                                               int N, int K, int r1, int r2)
{
    constexpr int NT = (BM/TM)*(BN/TN);   // 256
    __shared__ float As[BK][BM+4];
    __shared__ float Ws[BK][BN+4];

    const int tid = threadIdx.x;
    const int bn0 = blockIdx.x * BN;
    const int bm0 = blockIdx.y * BM;
    const int tx = tid % (BN/TN);
    const int ty = tid / (BN/TN);

    float acc[TM][TN];
    #pragma unroll
    for (int i = 0; i < TM; i++)
        #pragma unroll
        for (int j = 0; j < TN; j++) acc[i][j] = 0.f;

    for (int k0 = 0; k0 < K; k0 += BK) {
        #pragma unroll
        for (int idx = tid; idx < (BM*BK)/4; idx += NT) {
            int c = idx & (BK/4 - 1);
            int r = idx / (BK/4);
            int orow = bm0 + r;
            int arow = REMAP ? (orow % r1) * r2 + orow / r1 : orow;
            float4 a = *(const float4*)(A + (size_t)arow * K + k0 + c*4);
            As[c*4+0][r] = a.x; As[c*4+1][r] = a.y;
            As[c*4+2][r] = a.z; As[c*4+3][r] = a.w;
        }
        #pragma unroll
        for (int idx = tid; idx < (BN*BK)/4; idx += NT) {
            int c = idx & (BK/4 - 1);
            int r = idx / (BK/4);
            float4 a = *(const float4*)(W + (size_t)(bn0 + r) * K + k0 + c*4);
            Ws[c*4+0][r] = a.x; Ws[c*4+1][r] = a.y;
            Ws[c*4+2][r] = a.z; Ws[c*4+3][r] = a.w;
        }
        __syncthreads();

        #pragma unroll
        for (int kk = 0; kk < BK; kk++) {
            float av[TM], bv[TN];
            #pragma unroll
            for (int i = 0; i < TM; i += 4) {
                float4 t4 = *(const float4*)&As[kk][ty*TM + i];
                av[i] = t4.x; av[i+1] = t4.y; av[i+2] = t4.z; av[i+3] = t4.w;
            }
            #pragma unroll
            for (int j = 0; j < TN; j += 4) {
                float4 t4 = *(const float4*)&Ws[kk][tx*TN + j];
                bv[j] = t4.x; bv[j+1] = t4.y; bv[j+2] = t4.z; bv[j+3] = t4.w;
            }
            #pragma unroll
            for (int i = 0; i < TM; i++)
                #pragma unroll
                for (int j = 0; j < TN; j++)
                    acc[i][j] = fmaf(av[i], bv[j], acc[i][j]);
        }
        __syncthreads();
    }

    #pragma unroll
    for (int i = 0; i < TM; i++) {
        const int o = bm0 + ty*TM + i;
        float* orow = out + (size_t)o * N + bn0 + tx*TN;
        #pragma unroll
        for (int j = 0; j < TN; j += 4) {
            float4 r;
            r.x = acc[i][j+0]; r.y = acc[i][j+1]; r.z = acc[i][j+2]; r.w = acc[i][j+3];
            if (EPI == 3) {
                const float* rp = resid + (size_t)o * N + bn0 + tx*TN + j;
                r.x += rp[0]; r.y += rp[1]; r.z += rp[2]; r.w += rp[3];
            }
            *(float4*)(orow + j) = r;
        }
    }
}

// ---------------------------------------------------------------------------
// Split a fp32 array into bf16 hi/lo pair: hi = bf16(x), lo = bf16(x - hi).
// ---------------------------------------------------------------------------
__global__ __launch_bounds__(256) void split_bf16_kernel(const float* __restrict__ in,
                                                         u16* __restrict__ hi,
                                                         u16* __restrict__ lo,
                                                         int n4)
{
    for (int i = blockIdx.x * blockDim.x + threadIdx.x; i < n4;
         i += gridDim.x * blockDim.x) {
        float4 v = ((const float4*)in)[i];
        ushort4 h, l;
        h.x = f2bf(v.x); l.x = f2bf(v.x - bf2f(h.x));
        h.y = f2bf(v.y); l.y = f2bf(v.y - bf2f(h.y));
        h.z = f2bf(v.z); l.z = f2bf(v.z - bf2f(h.z));
        h.w = f2bf(v.w); l.w = f2bf(v.w - bf2f(h.w));
        ((ushort4*)hi)[i] = h;
        ((ushort4*)lo)[i] = l;
    }
}

// ---------------------------------------------------------------------------
// Split-bf16 MFMA GEMM (NT): C = Ah*Wh + Ah*Wl + Al*Wh  ~= fp32 A*W^T.
// Tile 128x128, BK=32, 256 thr = 4 waves, wave -> 64x64 subtile (4x4 frags of
// 16x16x32). Staging via global_load_lds (16B), LDS linear dest + XOR-swizzled
// GLOBAL source; ds_read applies the same involution: ps = ls ^ ((row>>1)&3)
// -> 2-way-max bank aliasing (free) instead of 8-way.
//   EPI 2: v = gelu(acc + bias); write bf16 split pair (outh,outl)   [MLP1]
//   EPI 1: v = acc + bias; write fp32 outf                           [MLP2]
// ---------------------------------------------------------------------------
__device__ __forceinline__ float gelu_exact(float v) {
    return 0.5f * v * (1.0f + erff(v * 0.70710678118654752f));
}

template<int EPI>
__global__ __launch_bounds__(256) void gemm_bf16s(const u16* __restrict__ Ah,
                                                  const u16* __restrict__ Al,
                                                  const u16* __restrict__ Wh,
                                                  const u16* __restrict__ Wl,
                                                  const float* __restrict__ bias,
                                                  float* outf,
                                                  u16* outh, u16* outl,
                                                  int N, int K)
{
    __shared__ u16 lAh[128*32], lAl[128*32], lWh[128*32], lWl[128*32];

    const int tid  = threadIdx.x;
    const int wave = tid >> 6;
    const int lane = tid & 63;
    const int bn0 = blockIdx.x * 128;
    const int bm0 = blockIdx.y * 128;
    const int wr = (wave >> 1) * 64;   // wave row offset in tile
    const int wc = (wave & 1) * 64;    // wave col offset in tile
    const int mrow = lane & 15;
    const int ls   = lane >> 4;        // logical 16B k-slot 0..3

    f32x4 acc[4][4];
    #pragma unroll
    for (int m = 0; m < 4; m++)
        #pragma unroll
        for (int n = 0; n < 4; n++)
            #pragma unroll
            for (int r = 0; r < 4; r++) acc[m][n][r] = 0.f;

    const u16* gA_h = Ah + (size_t)bm0 * K;
    const u16* gA_l = Al + (size_t)bm0 * K;
    const u16* gW_h = Wh + (size_t)bn0 * K;
    const u16* gW_l = Wl + (size_t)bn0 * K;

    for (int k0 = 0; k0 < K; k0 += 32) {
        // stage 4 x [128][32] bf16 tiles: 2 segments (16B) per thread per tile
        #pragma unroll
        for (int i = 0; i < 2; i++) {
            const int seg  = tid + i * 256;
            const int row  = seg >> 2;
            const int psl  = seg & 3;
            const int lsl  = psl ^ ((row >> 1) & 3);   // inverse-swizzle source
            const size_t go = (size_t)row * K + k0 + lsl * 8;
            u16* dst0 = &lAh[(size_t)(wave * 64 + i * 256) * 8];  // wave-uniform
            u16* dst1 = &lAl[(size_t)(wave * 64 + i * 256) * 8];
            u16* dst2 = &lWh[(size_t)(wave * 64 + i * 256) * 8];
            u16* dst3 = &lWl[(size_t)(wave * 64 + i * 256) * 8];
            __builtin_amdgcn_global_load_lds(
                (const __attribute__((address_space(1))) void*)(gA_h + go),
                (__attribute__((address_space(3))) void*)dst0, 16, 0, 0);
            __builtin_amdgcn_global_load_lds(
                (const __attribute__((address_space(1))) void*)(gA_l + go),
                (__attribute__((address_space(3))) void*)dst1, 16, 0, 0);
            __builtin_amdgcn_global_load_lds(
                (const __attribute__((address_space(1))) void*)(gW_h + go),
                (__attribute__((address_space(3))) void*)dst2, 16, 0, 0);
            __builtin_amdgcn_global_load_lds(
                (const __attribute__((address_space(1))) void*)(gW_l + go),
                (__attribute__((address_space(3))) void*)dst3, 16, 0, 0);
        }
        __syncthreads();   // drains vmcnt (global_load_lds) + orders LDS

        short8 ah[4], al[4], bh[4], bl[4];
        #pragma unroll
        for (int m = 0; m < 4; m++) {
            const int ra = wr + m*16 + mrow;
            const int ps = ls ^ ((ra >> 1) & 3);
            ah[m] = *(const short8*)&lAh[ra*32 + ps*8];
            al[m] = *(const short8*)&lAl[ra*32 + ps*8];
        }
        #pragma unroll
        for (int n = 0; n < 4; n++) {
            const int rb = wc + n*16 + mrow;
            const int ps = ls ^ ((rb >> 1) & 3);
            bh[n] = *(const short8*)&lWh[rb*32 + ps*8];
            bl[n] = *(const short8*)&lWl[rb*32 + ps*8];
        }

        // 3 groups of 16 MFMA; same acc touched every 16 -> no dep stalls
        #pragma unroll
        for (int m = 0; m < 4; m++)
            #pragma unroll
            for (int n = 0; n < 4; n++)
                acc[m][n] = __builtin_amdgcn_mfma_f32_16x16x32_bf16(ah[m], bh[n], acc[m][n], 0, 0, 0);
        #pragma unroll
        for (int m = 0; m < 4; m++)
            #pragma unroll
            for (int n = 0; n < 4; n++)
                acc[m][n] = __builtin_amdgcn_mfma_f32_16x16x32_bf16(ah[m], bl[n], acc[m][n], 0, 0, 0);
        #pragma unroll
        for (int m = 0; m < 4; m++)
            #pragma unroll
            for (int n = 0; n < 4; n++)
                acc[m][n] = __builtin_amdgcn_mfma_f32_16x16x32_bf16(al[m], bh[n], acc[m][n], 0, 0, 0);
        __syncthreads();
    }

    // epilogue: C/D layout col=lane&15, row=(lane>>4)*4+r  [m89/m91 verified]
    const int lrow = (lane >> 4) * 4;
    const int lcol = lane & 15;
    float bias_n[4];
    #pragma unroll
    for (int n = 0; n < 4; n++) bias_n[n] = bias[bn0 + wc + n*16 + lcol];

    #pragma unroll
    for (int m = 0; m < 4; m++) {
        #pragma unroll
        for (int n = 0; n < 4; n++) {
            const int col = bn0 + wc + n*16 + lcol;
            #pragma unroll
            for (int r = 0; r < 4; r++) {
                const int row = bm0 + wr + m*16 + lrow + r;
                float v = acc[m][n][r] + bias_n[n];
                if (EPI == 2) {
                    v = gelu_exact(v);
                    u16 h = f2bf(v);
                    u16 l = f2bf(v - bf2f(h));
                    outh[(size_t)row * N + col] = h;
                    outl[(size_t)row * N + col] = l;
                } else {
                    outf[(size_t)row * N + col] = v;
                }
            }
        }
    }
}

// ---------------------------------------------------------------------------
// Sequential state scan, latency-optimized. One block per batch (32 blocks),
// 1024 threads = 128 s-rows x 8 k-slices; each thread covers BOTH matvecs.
// - single barrier/step (h double-buffered in LDS)
// - inj prefetched one step ahead (global latency off the critical path)
// - h history buffered 8 steps in LDS (16-deep, 2 epochs), bulk-flushed ->
//   store-drain cost amortized 1/8
// - k-slices interleaved by 4 floats -> conflict-free LDS reads
// inj MAY ALIAS h_all: flush writes steps <= step, prefetch reads step+1.
// ---------------------------------------------------------------------------
__global__ __launch_bounds__(1024) void scan_kernel(const float* inj,
                                                    const float* __restrict__ gate_w,
                                                    const float* __restrict__ gate_b,
                                                    const float* __restrict__ state_flow,
                                                    float* h_all)
{
    const int b = blockIdx.x;
    const int t = threadIdx.x;
    const int s = t >> 3;       // 0..127
    const int p = t & 7;        // 0..7  (lane&7 within wave)

    // thread's k set: k = j*32 + p*4 + e, j=0..3, e=0..3 (16 k per matvec)
    float wg[16], wf[16];
    #pragma unroll
    for (int j = 0; j < 4; j++) {
        float4 a = *(const float4*)(gate_w     + (size_t)s * S_ + j*32 + p*4);
        float4 c = *(const float4*)(state_flow + (size_t)s * S_ + j*32 + p*4);
        wg[j*4+0] = a.x; wg[j*4+1] = a.y; wg[j*4+2] = a.z; wg[j*4+3] = a.w;
        wf[j*4+0] = c.x; wf[j*4+1] = c.y; wf[j*4+2] = c.z; wf[j*4+3] = c.w;
    }
    const float gb = gate_b[s];

    __shared__ __align__(16) float hbuf[2][S_];
    __shared__ float hist[16][S_];
    if (t < S_) hbuf[0][t] = 0.f;
    __syncthreads();

    const float* injb = inj   + (size_t)b * S_;
    float*       hab  = h_all + (size_t)b * S_;

    float hprev  = 0.f;                               // valid on p==0
    float curinj = (p == 0) ? injb[s] : 0.f;          // step 0
    int cur = 0;

    for (int step = 0; step < T_; step++) {
        // prefetch next step's injection (used next iteration)
        float nxtinj = 0.f;
        if (p == 0 && step + 1 < T_)
            nxtinj = injb[(size_t)(step + 1) * (B_ * S_) + s];

        float g0=0.f,g1=0.f,g2=0.f,g3=0.f, f0=0.f,f1=0.f,f2=0.f,f3=0.f;
        #pragma unroll
        for (int j = 0; j < 4; j++) {
            float4 hv = *(const float4*)&hbuf[cur][j*32 + p*4];
            g0 = fmaf(wg[j*4+0], hv.x, g0); f0 = fmaf(wf[j*4+0], hv.x, f0);
            g1 = fmaf(wg[j*4+1], hv.y, g1); f1 = fmaf(wf[j*4+1], hv.y, f1);
            g2 = fmaf(wg[j*4+2], hv.z, g2); f2 = fmaf(wf[j*4+2], hv.z, f2);
            g3 = fmaf(wg[j*4+3], hv.w, g3); f3 = fmaf(wf[j*4+3], hv.w, f3);
        }
        float dg = (g0+g1)+(g2+g3);
        float df = (f0+f1)+(f2+f3);
        dg += __shfl_xor(dg, 1); df += __shfl_xor(df, 1);
        dg += __shfl_xor(dg, 2); df += __shfl_xor(df, 2);
        dg += __shfl_xor(dg, 4); df += __shfl_xor(df, 4);

        if (p == 0) {
            float g  = 1.f / (1.f + expf(-(dg + gb + curinj)));
            float hn = (1.f - g) * hprev + g * df;
            hprev = hn;
            hbuf[cur ^ 1][s]    = hn;
            hist[step & 15][s]  = hn;
        }
        curinj = nxtinj;
        __syncthreads();

        if ((step & 7) == 7) {
            // flush 8 steps (slots base..base+7; next epoch writes other half)
            const int base = step & 8;
            const int q  = t >> 7;       // 0..7
            const int ss = t & 127;
            hab[(size_t)(step - 7 + q) * (B_ * S_) + ss] = hist[base + q][ss];
        }
        cur ^= 1;
    }
}

// ---------------------------------------------------------------------------
extern "C" void kernel_launch(void* const* d_in, const int* in_sizes, int n_in,
                              void* d_out, int out_size, void* d_ws, size_t ws_size,
                              hipStream_t stream)
{
    const float* x          = (const float*)d_in[0];
    const float* ln1_w      = (const float*)d_in[1];
    const float* ln1_b      = (const float*)d_in[2];
    const float* state_flow = (const float*)d_in[3];
    const float* injection  = (const float*)d_in[4];
    const float* readout    = (const float*)d_in[5];
    const float* gate_w     = (const float*)d_in[6];
    const float* gate_b     = (const float*)d_in[7];
    const float* mlp_w1     = (const float*)d_in[8];
    const float* mlp_b1     = (const float*)d_in[9];
    const float* mlp_w2     = (const float*)d_in[10];
    const float* mlp_b2     = (const float*)d_in[11];
    const float* ln2_w      = (const float*)d_in[12];
    const float* ln2_b      = (const float*)d_in[13];
    float* out = (float*)d_out;
    float* ws  = (float*)d_ws;

    const size_t MD  = (size_t)M_ * D_;       // 33.55M floats
    const size_t TBS = (size_t)T_ * B_ * S_;  // 4.19M floats
    const size_t HD  = (size_t)H_ * D_;       // 4.19M elements

    // pick largest MLP row-chunk that fits the workspace
    int MC = 8192;
    while (MC > 512) {
        size_t need = (MD + TBS) * 4
                    + (4 * HD + 2 * (size_t)MC * D_ + 2 * (size_t)MC * H_) * 2;
        if (need <= ws_size) break;
        MC >>= 1;
    }

    // workspace layout
    float* xb  = ws;                          // [M,D] f32: LN1 out -> post-state -> MLP out
    float* inj = xb + MD;                     // [T,B,S] f32: injection -> (in place) h_all
    u16*  w1h = (u16*)(inj + TBS);            // [H,D] bf16 hi
    u16*  w1l = w1h + HD;
    u16*  w2h = w1l + HD;                     // [D,H]
    u16*  w2l = w2h + HD;
    u16*  xch = w2l + HD;                     // [MC,D] bf16 hi/lo of MLP1 input chunk
    u16*  xcl = xch + (size_t)MC * D_;
    u16*  hh  = xcl + (size_t)MC * D_;        // [MC,H] bf16 hi/lo of gelu hidden
    u16*  hl  = hh  + (size_t)MC * H_;

    // weight splits (once per call)
    split_bf16_kernel<<<2048, 256, 0, stream>>>(mlp_w1, w1h, w1l, (int)(HD / 4));
    split_bf16_kernel<<<2048, 256, 0, stream>>>(mlp_w2, w2h, w2l, (int)(HD / 4));

    // A: xb = LN1(x)
    ln_kernel<false><<<M_, 256, 0, stream>>>(x, ln1_w, ln1_b, xb);

    // B: inj[t*B+b][s] = sum_d xb[b*T+t][d] * injection[s][d]
    gemm_nt<64,64,16,4,4,0,true><<<dim3(S_/64, M_/64), 256, 0, stream>>>(
        xb, injection, nullptr, inj, S_, D_, B_, T_);

    // C: sequential gated state scan, in place: inj -> h_all
    scan_kernel<<<B_, 1024, 0, stream>>>(inj, gate_w, gate_b, state_flow, inj);

    // D (in place): xb[b*T+t][d] += sum_s inj[t*B+b][s]*readout[d][s]
    gemm_nt<64,64,16,4,4,3,true><<<dim3(D_/64, M_/64), 256, 0, stream>>>(
        inj, readout, xb, xb, D_, S_, T_, B_);

    // E/F: MLP in split-bf16 MFMA, chunked over rows; writes back into xb
    for (int c = 0; c < M_ / MC; c++) {
        float* xbc = xb + (size_t)c * MC * D_;
        split_bf16_kernel<<<2048, 256, 0, stream>>>(xbc, xch, xcl, MC * D_ / 4);
        gemm_bf16s<2><<<dim3(H_/128, MC/128), 256, 0, stream>>>(
            xch, xcl, w1h, w1l, mlp_b1, nullptr, hh, hl, H_, D_);
        gemm_bf16s<1><<<dim3(D_/128, MC/128), 256, 0, stream>>>(
            hh, hl, w2h, w2l, mlp_b2, xbc, nullptr, nullptr, D_, H_);
    }

    // G: out = xb + LN2(xb)
    ln_kernel<true><<<M_, 256, 0, stream>>>(xb, ln2_w, ln2_b, out);
}

// Round 4
// 2063.810 us; speedup vs baseline: 4.7540x; 1.6409x over previous
//
#include <hip/hip_runtime.h>
#include <math.h>

#define B_ 32
#define T_ 1024
#define D_ 1024
#define S_ 128
#define H_ 4096
#define M_ (B_*T_)          // 32768 rows
#define LN_EPS 1e-5f

typedef unsigned short u16;
typedef unsigned int   u32;
typedef short short8 __attribute__((ext_vector_type(8)));
typedef float f32x4  __attribute__((ext_vector_type(4)));

// bf16 round-to-nearest-even helpers
__device__ __forceinline__ u16 f2bf(float x) {
    u32 u = __float_as_uint(x);
    u += 0x7FFFu + ((u >> 16) & 1u);
    return (u16)(u >> 16);
}
__device__ __forceinline__ float bf2f(u16 h) {
    return __uint_as_float(((u32)h) << 16);
}

// ---------------------------------------------------------------------------
// LayerNorm over last dim (D=1024). One block (256 thr) per row.
// ---------------------------------------------------------------------------
template<bool ADD_INPUT>
__global__ __launch_bounds__(256) void ln_kernel(const float* __restrict__ x,
                                                 const float* __restrict__ w,
                                                 const float* __restrict__ b,
                                                 float* __restrict__ out)
{
    const int row = blockIdx.x;
    const int tid = threadIdx.x;
    const float4* xr = (const float4*)(x + (size_t)row * D_);
    float4 v = xr[tid];

    float s  = v.x + v.y + v.z + v.w;
    float ss = v.x*v.x + v.y*v.y + v.z*v.z + v.w*v.w;
    #pragma unroll
    for (int off = 32; off; off >>= 1) {
        s  += __shfl_down(s,  off);
        ss += __shfl_down(ss, off);
    }
    __shared__ float redS[4], redS2[4];
    __shared__ float mu_s, rstd_s;
    const int wave = tid >> 6;
    if ((tid & 63) == 0) { redS[wave] = s; redS2[wave] = ss; }
    __syncthreads();
    if (tid == 0) {
        float s0 = redS[0]+redS[1]+redS[2]+redS[3];
        float s1 = redS2[0]+redS2[1]+redS2[2]+redS2[3];
        float mu = s0 * (1.0f / D_);
        float var = s1 * (1.0f / D_) - mu * mu;
        mu_s = mu;
        rstd_s = rsqrtf(var + LN_EPS);
    }
    __syncthreads();
    const float mu = mu_s, rstd = rstd_s;

    float4 wv = ((const float4*)w)[tid];
    float4 bv = ((const float4*)b)[tid];
    float4 o;
    o.x = (v.x - mu) * rstd * wv.x + bv.x;
    o.y = (v.y - mu) * rstd * wv.y + bv.y;
    o.z = (v.z - mu) * rstd * wv.z + bv.z;
    o.w = (v.w - mu) * rstd * wv.w + bv.w;
    if (ADD_INPUT) { o.x += v.x; o.y += v.y; o.z += v.z; o.w += v.w; }
    ((float4*)(out + (size_t)row * D_))[tid] = o;
}

// ---------------------------------------------------------------------------
// fp32 NT GEMM (for the two small S=128 GEMMs feeding the sigmoid path).
//   REMAP: arow = (o % r1) * r2 + o / r1
//   EPI: 0 none | 3 +resid[o][n]  (resid/out may alias)
// ---------------------------------------------------------------------------
template<int BM,int BN,int BK,int TM,int TN,int EPI,bool REMAP>
__global__ __launch_bounds__(256) void gemm_nt(const float* __restrict__ A,
                                               const float* __restrict__ W,
                                               const float* resid,
                                               float* out,
                                               int N, int K, int r1, int r2)
{
    constexpr int NT = (BM/TM)*(BN/TN);   // 256
    __shared__ float As[BK][BM+4];
    __shared__ float Ws[BK][BN+4];

    const int tid = threadIdx.x;
    const int bn0 = blockIdx.x * BN;
    const int bm0 = blockIdx.y * BM;
    const int tx = tid % (BN/TN);
    const int ty = tid / (BN/TN);

    float acc[TM][TN];
    #pragma unroll
    for (int i = 0; i < TM; i++)
        #pragma unroll
        for (int j = 0; j < TN; j++) acc[i][j] = 0.f;

    for (int k0 = 0; k0 < K; k0 += BK) {
        #pragma unroll
        for (int idx = tid; idx < (BM*BK)/4; idx += NT) {
            int c = idx & (BK/4 - 1);
            int r = idx / (BK/4);
            int orow = bm0 + r;
            int arow = REMAP ? (orow % r1) * r2 + orow / r1 : orow;
            float4 a = *(const float4*)(A + (size_t)arow * K + k0 + c*4);
            As[c*4+0][r] = a.x; As[c*4+1][r] = a.y;
            As[c*4+2][r] = a.z; As[c*4+3][r] = a.w;
        }
        #pragma unroll
        for (int idx = tid; idx < (BN*BK)/4; idx += NT) {
            int c = idx & (BK/4 - 1);
            int r = idx / (BK/4);
            float4 a = *(const float4*)(W + (size_t)(bn0 + r) * K + k0 + c*4);
            Ws[c*4+0][r] = a.x; Ws[c*4+1][r] = a.y;
            Ws[c*4+2][r] = a.z; Ws[c*4+3][r] = a.w;
        }
        __syncthreads();

        #pragma unroll
        for (int kk = 0; kk < BK; kk++) {
            float av[TM], bv[TN];
            #pragma unroll
            for (int i = 0; i < TM; i += 4) {
                float4 t4 = *(const float4*)&As[kk][ty*TM + i];
                av[i] = t4.x; av[i+1] = t4.y; av[i+2] = t4.z; av[i+3] = t4.w;
            }
            #pragma unroll
            for (int j = 0; j < TN; j += 4) {
                float4 t4 = *(const float4*)&Ws[kk][tx*TN + j];
                bv[j] = t4.x; bv[j+1] = t4.y; bv[j+2] = t4.z; bv[j+3] = t4.w;
            }
            #pragma unroll
            for (int i = 0; i < TM; i++)
                #pragma unroll
                for (int j = 0; j < TN; j++)
                    acc[i][j] = fmaf(av[i], bv[j], acc[i][j]);
        }
        __syncthreads();
    }

    #pragma unroll
    for (int i = 0; i < TM; i++) {
        const int o = bm0 + ty*TM + i;
        float* orow = out + (size_t)o * N + bn0 + tx*TN;
        #pragma unroll
        for (int j = 0; j < TN; j += 4) {
            float4 r;
            r.x = acc[i][j+0]; r.y = acc[i][j+1]; r.z = acc[i][j+2]; r.w = acc[i][j+3];
            if (EPI == 3) {
                const float* rp = resid + (size_t)o * N + bn0 + tx*TN + j;
                r.x += rp[0]; r.y += rp[1]; r.z += rp[2]; r.w += rp[3];
            }
            *(float4*)(orow + j) = r;
        }
    }
}

// ---------------------------------------------------------------------------
// fp32 -> bf16 cast (round-to-nearest-even), float4-vectorized.
// ---------------------------------------------------------------------------
__global__ __launch_bounds__(256) void cast_bf16_kernel(const float* __restrict__ in,
                                                        u16* __restrict__ out, int n4)
{
    for (int i = blockIdx.x * blockDim.x + threadIdx.x; i < n4;
         i += gridDim.x * blockDim.x) {
        float4 v = ((const float4*)in)[i];
        ushort4 h;
        h.x = f2bf(v.x); h.y = f2bf(v.y); h.z = f2bf(v.z); h.w = f2bf(v.w);
        ((ushort4*)out)[i] = h;
    }
}

// ---------------------------------------------------------------------------
// Detect flow == c * I (exact bit equality). Writes {flag, c} to flagc.
// Runs every call (ws is re-poisoned); result is data-derived, graph-safe.
// ---------------------------------------------------------------------------
__global__ __launch_bounds__(256) void diag_check_kernel(const float* __restrict__ flow,
                                                         float* __restrict__ flagc)
{
    __shared__ int bad;
    if (threadIdx.x == 0) bad = 0;
    __syncthreads();
    const float c = flow[0];
    for (int i = threadIdx.x; i < S_ * S_; i += 256) {
        const int r = i >> 7, cc = i & 127;
        const float expect = (r == cc) ? c : 0.f;
        if (__float_as_uint(flow[i]) != __float_as_uint(expect)) bad = 1;
    }
    __syncthreads();
    if (threadIdx.x == 0) { flagc[0] = bad ? 0.f : 1.f; flagc[1] = c; }
}

// ---------------------------------------------------------------------------
// Pure-bf16 MFMA GEMM (NT), m97 structure: 128x128 tile, BK=32, 4 waves,
// global_load_lds 16B staging, linear LDS dest + inverse-swizzled global src,
// swizzled ds_read (involution ps = ls ^ ((row>>1)&3)).
//   EPI 2: v = gelu(acc + bias); write bf16 outh          [MLP1]
//   EPI 1: v = acc + bias;       write fp32 outf          [MLP2]
// ---------------------------------------------------------------------------
__device__ __forceinline__ float gelu_exact(float v) {
    return 0.5f * v * (1.0f + erff(v * 0.70710678118654752f));
}

template<int EPI>
__global__ __launch_bounds__(256) void gemm_b16(const u16* __restrict__ A,
                                                const u16* __restrict__ W,
                                                const float* __restrict__ bias,
                                                float* outf, u16* outh,
                                                int N, int K)
{
    __shared__ u16 lA[128*32], lW[128*32];

    const int tid  = threadIdx.x;
    const int wave = tid >> 6;
    const int lane = tid & 63;
    const int bn0 = blockIdx.x * 128;
    const int bm0 = blockIdx.y * 128;
    const int wr = (wave >> 1) * 64;
    const int wc = (wave & 1) * 64;
    const int mrow = lane & 15;
    const int ls   = lane >> 4;        // logical 16B k-slot 0..3

    f32x4 acc[4][4];
    #pragma unroll
    for (int m = 0; m < 4; m++)
        #pragma unroll
        for (int n = 0; n < 4; n++)
            #pragma unroll
            for (int r = 0; r < 4; r++) acc[m][n][r] = 0.f;

    const u16* gA = A + (size_t)bm0 * K;
    const u16* gW = W + (size_t)bn0 * K;

    for (int k0 = 0; k0 < K; k0 += 32) {
        #pragma unroll
        for (int i = 0; i < 2; i++) {
            const int seg  = tid + i * 256;          // 0..511
            const int row  = seg >> 2;
            const int psl  = seg & 3;                // physical LDS slot
            const int lsl  = psl ^ ((row >> 1) & 3); // logical k-slot fetched
            const size_t go = (size_t)row * K + k0 + lsl * 8;
            u16* dstA = &lA[(size_t)(wave * 64 + i * 256) * 8];  // wave-uniform
            u16* dstW = &lW[(size_t)(wave * 64 + i * 256) * 8];
            __builtin_amdgcn_global_load_lds(
                (const __attribute__((address_space(1))) void*)(gA + go),
                (__attribute__((address_space(3))) void*)dstA, 16, 0, 0);
            __builtin_amdgcn_global_load_lds(
                (const __attribute__((address_space(1))) void*)(gW + go),
                (__attribute__((address_space(3))) void*)dstW, 16, 0, 0);
        }
        __syncthreads();   // drains vmcnt + orders LDS

        short8 ah[4], bh[4];
        #pragma unroll
        for (int m = 0; m < 4; m++) {
            const int ra = wr + m*16 + mrow;
            const int ps = ls ^ ((ra >> 1) & 3);
            ah[m] = *(const short8*)&lA[ra*32 + ps*8];
        }
        #pragma unroll
        for (int n = 0; n < 4; n++) {
            const int rb = wc + n*16 + mrow;
            const int ps = ls ^ ((rb >> 1) & 3);
            bh[n] = *(const short8*)&lW[rb*32 + ps*8];
        }

        #pragma unroll
        for (int m = 0; m < 4; m++)
            #pragma unroll
            for (int n = 0; n < 4; n++)
                acc[m][n] = __builtin_amdgcn_mfma_f32_16x16x32_bf16(ah[m], bh[n], acc[m][n], 0, 0, 0);
        __syncthreads();
    }

    // epilogue: C/D layout col=lane&15, row=(lane>>4)*4+r
    const int lrow = (lane >> 4) * 4;
    const int lcol = lane & 15;
    float bias_n[4];
    #pragma unroll
    for (int n = 0; n < 4; n++) bias_n[n] = bias[bn0 + wc + n*16 + lcol];

    #pragma unroll
    for (int m = 0; m < 4; m++) {
        #pragma unroll
        for (int n = 0; n < 4; n++) {
            const int col = bn0 + wc + n*16 + lcol;
            #pragma unroll
            for (int r = 0; r < 4; r++) {
                const int row = bm0 + wr + m*16 + lrow + r;
                float v = acc[m][n][r] + bias_n[n];
                if (EPI == 2) {
                    v = gelu_exact(v);
                    outh[(size_t)row * N + col] = f2bf(v);
                } else {
                    outf[(size_t)row * N + col] = v;
                }
            }
        }
    }
}

// ---------------------------------------------------------------------------
// Sequential state scan. One block per batch (32 blocks), 1024 threads =
// 128 s-rows x 8 k-slices. Fast path (flow == c*I, runtime-detected):
// only the gate matvec is computed; h@flow.T == c*h folds into one FMA.
// Fallback computes both matvecs (correct for arbitrary flow).
// - single barrier/step, h double-buffered in LDS
// - inj prefetched one step ahead
// - h history buffered 8 steps (16-deep hist), bulk-flushed (1/8 steps)
// inj MAY ALIAS h_all: flush writes steps <= step, prefetch reads step+1.
// ---------------------------------------------------------------------------
__global__ __launch_bounds__(1024) void scan_kernel(const float* inj,
                                                    const float* __restrict__ gate_w,
                                                    const float* __restrict__ gate_b,
                                                    const float* __restrict__ state_flow,
                                                    const float* __restrict__ flagc,
                                                    float* h_all)
{
    const int b = blockIdx.x;
    const int t = threadIdx.x;
    const int s = t >> 3;       // 0..127
    const int p = t & 7;        // 0..7

    const bool diag = (flagc[0] != 0.f);
    const float cdiag = flagc[1];

    float wg[16];
    #pragma unroll
    for (int j = 0; j < 4; j++) {
        float4 a = *(const float4*)(gate_w + (size_t)s * S_ + j*32 + p*4);
        wg[j*4+0] = a.x; wg[j*4+1] = a.y; wg[j*4+2] = a.z; wg[j*4+3] = a.w;
    }
    const float gb = gate_b[s];

    __shared__ __align__(16) float hbuf[2][S_];
    __shared__ float hist[16][S_];
    if (t < S_) hbuf[0][t] = 0.f;
    __syncthreads();

    const float* injb = inj   + (size_t)b * S_;
    float*       hab  = h_all + (size_t)b * S_;

    float hprev  = 0.f;                               // valid on p==0
    float curinj = (p == 0) ? injb[s] : 0.f;
    int cur = 0;

    if (diag) {
        for (int step = 0; step < T_; step++) {
            float nxtinj = 0.f;
            if (p == 0 && step + 1 < T_)
                nxtinj = injb[(size_t)(step + 1) * (B_ * S_) + s];

            float g0=0.f,g1=0.f,g2=0.f,g3=0.f;
            #pragma unroll
            for (int j = 0; j < 4; j++) {
                float4 hv = *(const float4*)&hbuf[cur][j*32 + p*4];
                g0 = fmaf(wg[j*4+0], hv.x, g0);
                g1 = fmaf(wg[j*4+1], hv.y, g1);
                g2 = fmaf(wg[j*4+2], hv.z, g2);
                g3 = fmaf(wg[j*4+3], hv.w, g3);
            }
            float dg = (g0+g1)+(g2+g3);
            dg += __shfl_xor(dg, 1);
            dg += __shfl_xor(dg, 2);
            dg += __shfl_xor(dg, 4);

            if (p == 0) {
                float g  = 1.f / (1.f + expf(-(dg + gb + curinj)));
                float hn = hprev * (1.f - g * (1.f - cdiag)); // (1-g)h + g*c*h
                hprev = hn;
                hbuf[cur ^ 1][s]   = hn;
                hist[step & 15][s] = hn;
            }
            curinj = nxtinj;
            __syncthreads();

            if ((step & 7) == 7) {
                const int base = step & 8;
                const int q  = t >> 7;
                const int ss = t & 127;
                hab[(size_t)(step - 7 + q) * (B_ * S_) + ss] = hist[base + q][ss];
            }
            cur ^= 1;
        }
    } else {
        float wf[16];
        #pragma unroll
        for (int j = 0; j < 4; j++) {
            float4 c4 = *(const float4*)(state_flow + (size_t)s * S_ + j*32 + p*4);
            wf[j*4+0] = c4.x; wf[j*4+1] = c4.y; wf[j*4+2] = c4.z; wf[j*4+3] = c4.w;
        }
        for (int step = 0; step < T_; step++) {
            float nxtinj = 0.f;
            if (p == 0 && step + 1 < T_)
                nxtinj = injb[(size_t)(step + 1) * (B_ * S_) + s];

            float g0=0.f,g1=0.f,g2=0.f,g3=0.f, f0=0.f,f1=0.f,f2=0.f,f3=0.f;
            #pragma unroll
            for (int j = 0; j < 4; j++) {
                float4 hv = *(const float4*)&hbuf[cur][j*32 + p*4];
                g0 = fmaf(wg[j*4+0], hv.x, g0); f0 = fmaf(wf[j*4+0], hv.x, f0);
                g1 = fmaf(wg[j*4+1], hv.y, g1); f1 = fmaf(wf[j*4+1], hv.y, f1);
                g2 = fmaf(wg[j*4+2], hv.z, g2); f2 = fmaf(wf[j*4+2], hv.z, f2);
                g3 = fmaf(wg[j*4+3], hv.w, g3); f3 = fmaf(wf[j*4+3], hv.w, f3);
            }
            float dg = (g0+g1)+(g2+g3);
            float df = (f0+f1)+(f2+f3);
            dg += __shfl_xor(dg, 1); df += __shfl_xor(df, 1);
            dg += __shfl_xor(dg, 2); df += __shfl_xor(df, 2);
            dg += __shfl_xor(dg, 4); df += __shfl_xor(df, 4);

            if (p == 0) {
                float g  = 1.f / (1.f + expf(-(dg + gb + curinj)));
                float hn = (1.f - g) * hprev + g * df;
                hprev = hn;
                hbuf[cur ^ 1][s]   = hn;
                hist[step & 15][s] = hn;
            }
            curinj = nxtinj;
            __syncthreads();

            if ((step & 7) == 7) {
                const int base = step & 8;
                const int q  = t >> 7;
                const int ss = t & 127;
                hab[(size_t)(step - 7 + q) * (B_ * S_) + ss] = hist[base + q][ss];
            }
            cur ^= 1;
        }
    }
}

// ---------------------------------------------------------------------------
extern "C" void kernel_launch(void* const* d_in, const int* in_sizes, int n_in,
                              void* d_out, int out_size, void* d_ws, size_t ws_size,
                              hipStream_t stream)
{
    const float* x          = (const float*)d_in[0];
    const float* ln1_w      = (const float*)d_in[1];
    const float* ln1_b      = (const float*)d_in[2];
    const float* state_flow = (const float*)d_in[3];
    const float* injection  = (const float*)d_in[4];
    const float* readout    = (const float*)d_in[5];
    const float* gate_w     = (const float*)d_in[6];
    const float* gate_b     = (const float*)d_in[7];
    const float* mlp_w1     = (const float*)d_in[8];
    const float* mlp_b1     = (const float*)d_in[9];
    const float* mlp_w2     = (const float*)d_in[10];
    const float* mlp_b2     = (const float*)d_in[11];
    const float* ln2_w      = (const float*)d_in[12];
    const float* ln2_b      = (const float*)d_in[13];
    float* out = (float*)d_out;
    float* ws  = (float*)d_ws;

    const size_t MD  = (size_t)M_ * D_;       // 33.55M floats
    const size_t TBS = (size_t)T_ * B_ * S_;  // 4.19M floats
    const size_t HD  = (size_t)H_ * D_;       // 4.19M elements

    // pick largest MLP row-chunk that fits the workspace
    int MC = 8192;
    while (MC > 512) {
        size_t need = (MD + TBS) * 4
                    + (2 * HD + (size_t)MC * D_ + (size_t)MC * H_) * 2 + 64;
        if (need <= ws_size) break;
        MC >>= 1;
    }

    // workspace layout
    float* xb  = ws;                          // [M,D] f32
    float* inj = xb + MD;                     // [T,B,S] f32 -> (in place) h_all
    u16*  w1b = (u16*)(inj + TBS);            // [H,D] bf16
    u16*  w2b = w1b + HD;                     // [D,H] bf16
    u16*  xcb = w2b + HD;                     // [MC,D] bf16 MLP1 input chunk
    u16*  hb  = xcb + (size_t)MC * D_;        // [MC,H] bf16 gelu hidden
    float* flagc = (float*)(hb + (size_t)MC * H_);  // {flag, c}

    // flow-structure detection + weight casts (once per call)
    diag_check_kernel<<<1, 256, 0, stream>>>(state_flow, flagc);
    cast_bf16_kernel<<<2048, 256, 0, stream>>>(mlp_w1, w1b, (int)(HD / 4));
    cast_bf16_kernel<<<2048, 256, 0, stream>>>(mlp_w2, w2b, (int)(HD / 4));

    // A: xb = LN1(x)
    ln_kernel<false><<<M_, 256, 0, stream>>>(x, ln1_w, ln1_b, xb);

    // B: inj[t*B+b][s] = sum_d xb[b*T+t][d] * injection[s][d]   (fp32)
    gemm_nt<64,64,16,4,4,0,true><<<dim3(S_/64, M_/64), 256, 0, stream>>>(
        xb, injection, nullptr, inj, S_, D_, B_, T_);

    // C: sequential gated state scan, in place: inj -> h_all
    scan_kernel<<<B_, 1024, 0, stream>>>(inj, gate_w, gate_b, state_flow, flagc, inj);

    // D (in place): xb[b*T+t][d] += sum_s inj[t*B+b][s]*readout[d][s]   (fp32)
    gemm_nt<64,64,16,4,4,3,true><<<dim3(D_/64, M_/64), 256, 0, stream>>>(
        inj, readout, xb, xb, D_, S_, T_, B_);

    // E/F: MLP in pure bf16 MFMA, chunked; writes back into xb in place
    for (int c = 0; c < M_ / MC; c++) {
        float* xbc = xb + (size_t)c * MC * D_;
        cast_bf16_kernel<<<2048, 256, 0, stream>>>(xbc, xcb, MC * D_ / 4);
        gemm_b16<2><<<dim3(H_/128, MC/128), 256, 0, stream>>>(
            xcb, w1b, mlp_b1, nullptr, hb, H_, D_);
        gemm_b16<1><<<dim3(D_/128, MC/128), 256, 0, stream>>>(
            hb, w2b, mlp_b2, xbc, nullptr, D_, H_);
    }

    // G: out = xb + LN2(xb)
    ln_kernel<true><<<M_, 256, 0, stream>>>(xb, ln2_w, ln2_b, out);
}

// Round 5
// 1142.114 us; speedup vs baseline: 8.5904x; 1.8070x over previous
//
#include <hip/hip_runtime.h>
#include <math.h>

#define B_ 32
#define T_ 1024
#define D_ 1024
#define S_ 128
#define H_ 4096
#define M_ (B_*T_)          // 32768 rows
#define LN_EPS 1e-5f

typedef unsigned short u16;
typedef unsigned int   u32;
typedef short short8 __attribute__((ext_vector_type(8)));
typedef float f32x4  __attribute__((ext_vector_type(4)));

// bf16 round-to-nearest-even
__device__ __forceinline__ u16 f2bf(float x) {
    u32 u = __float_as_uint(x);
    u += 0x7FFFu + ((u >> 16) & 1u);
    return (u16)(u >> 16);
}

// ---------------------------------------------------------------------------
// NOTE: the reference's state_update is identically ZERO for all inputs:
// h0 = 0 and h_new = (1-g)*h + g*(h@flow^T) is multiplicative in h, so
// h == 0 for all t and ys == 0. The block reduces to
//   x1 = LN1(x); h = gelu(x1@W1^T+b1); x3 = h@W2^T+b2; out = x3 + LN2(x3).
// ---------------------------------------------------------------------------

// ---------------------------------------------------------------------------
// LayerNorm over last dim (D=1024). One block (256 thr) per row.
// OUT_BF16: write ushort4 bf16 (MLP1 input). ADD_INPUT: out = x + LN(x)*w+b,
// may run in place (x aliases outp) -> no __restrict__ on x/outp.
// ---------------------------------------------------------------------------
template<bool OUT_BF16, bool ADD_INPUT>
__global__ __launch_bounds__(256) void ln_kernel(const float* x,
                                                 const float* __restrict__ w,
                                                 const float* __restrict__ b,
                                                 void* outp)
{
    const int row = blockIdx.x;
    const int tid = threadIdx.x;
    const float4* xr = (const float4*)(x + (size_t)row * D_);
    float4 v = xr[tid];

    float s  = v.x + v.y + v.z + v.w;
    float ss = v.x*v.x + v.y*v.y + v.z*v.z + v.w*v.w;
    #pragma unroll
    for (int off = 32; off; off >>= 1) {
        s  += __shfl_down(s,  off);
        ss += __shfl_down(ss, off);
    }
    __shared__ float redS[4], redS2[4];
    __shared__ float mu_s, rstd_s;
    const int wave = tid >> 6;
    if ((tid & 63) == 0) { redS[wave] = s; redS2[wave] = ss; }
    __syncthreads();
    if (tid == 0) {
        float s0 = redS[0]+redS[1]+redS[2]+redS[3];
        float s1 = redS2[0]+redS2[1]+redS2[2]+redS2[3];
        float mu = s0 * (1.0f / D_);
        float var = s1 * (1.0f / D_) - mu * mu;
        mu_s = mu;
        rstd_s = rsqrtf(var + LN_EPS);
    }
    __syncthreads();
    const float mu = mu_s, rstd = rstd_s;

    float4 wv = ((const float4*)w)[tid];
    float4 bv = ((const float4*)b)[tid];
    float4 o;
    o.x = (v.x - mu) * rstd * wv.x + bv.x;
    o.y = (v.y - mu) * rstd * wv.y + bv.y;
    o.z = (v.z - mu) * rstd * wv.z + bv.z;
    o.w = (v.w - mu) * rstd * wv.w + bv.w;
    if (ADD_INPUT) { o.x += v.x; o.y += v.y; o.z += v.z; o.w += v.w; }

    if (OUT_BF16) {
        ushort4 h;
        h.x = f2bf(o.x); h.y = f2bf(o.y); h.z = f2bf(o.z); h.w = f2bf(o.w);
        ((ushort4*)((u16*)outp + (size_t)row * D_))[tid] = h;
    } else {
        ((float4*)((float*)outp + (size_t)row * D_))[tid] = o;
    }
}

// ---------------------------------------------------------------------------
// fp32 -> bf16 cast (weights), float4-vectorized.
// ---------------------------------------------------------------------------
__global__ __launch_bounds__(256) void cast_bf16_kernel(const float* __restrict__ in,
                                                        u16* __restrict__ out, int n4)
{
    for (int i = blockIdx.x * blockDim.x + threadIdx.x; i < n4;
         i += gridDim.x * blockDim.x) {
        float4 v = ((const float4*)in)[i];
        ushort4 h;
        h.x = f2bf(v.x); h.y = f2bf(v.y); h.z = f2bf(v.z); h.w = f2bf(v.w);
        ((ushort4*)out)[i] = h;
    }
}

// ---------------------------------------------------------------------------
// Pure-bf16 MFMA GEMM (NT), m97 structure: 128x128 tile, BK=32, 4 waves,
// global_load_lds 16B staging, linear LDS dest + inverse-swizzled global src,
// swizzled ds_read (involution ps = ls ^ ((row>>1)&3)) -> 0 bank conflicts.
// XCD-aware block swizzle (nwg % 8 == 0 at all call sites; gx = 1<<LGX).
//   EPI 2: v = gelu(acc + bias); write bf16 outh          [MLP1]
//   EPI 1: v = acc + bias;       write fp32 outf          [MLP2]
// ---------------------------------------------------------------------------
__device__ __forceinline__ float gelu_exact(float v) {
    return 0.5f * v * (1.0f + erff(v * 0.70710678118654752f));
}

template<int EPI, int LGX>
__global__ __launch_bounds__(256) void gemm_b16(const u16* __restrict__ A,
                                                const u16* __restrict__ W,
                                                const float* __restrict__ bias,
                                                float* outf, u16* outh,
                                                int N, int K)
{
    __shared__ u16 lA[128*32], lW[128*32];

    const int tid  = threadIdx.x;
    const int wave = tid >> 6;
    const int lane = tid & 63;

    // XCD swizzle: consecutive swizzled ids land on one XCD -> L2 panel reuse
    const int nwg = gridDim.x * gridDim.y;
    int bid = blockIdx.y * gridDim.x + blockIdx.x;
    bid = (bid & 7) * (nwg >> 3) + (bid >> 3);
    const int bn0 = (bid & ((1 << LGX) - 1)) * 128;
    const int bm0 = (bid >> LGX) * 128;

    const int wr = (wave >> 1) * 64;
    const int wc = (wave & 1) * 64;
    const int mrow = lane & 15;
    const int ls   = lane >> 4;        // logical 16B k-slot 0..3

    f32x4 acc[4][4];
    #pragma unroll
    for (int m = 0; m < 4; m++)
        #pragma unroll
        for (int n = 0; n < 4; n++)
            #pragma unroll
            for (int r = 0; r < 4; r++) acc[m][n][r] = 0.f;

    const u16* gA = A + (size_t)bm0 * K;
    const u16* gW = W + (size_t)bn0 * K;

    for (int k0 = 0; k0 < K; k0 += 32) {
        #pragma unroll
        for (int i = 0; i < 2; i++) {
            const int seg  = tid + i * 256;          // 0..511
            const int row  = seg >> 2;
            const int psl  = seg & 3;                // physical LDS slot
            const int lsl  = psl ^ ((row >> 1) & 3); // logical k-slot fetched
            const size_t go = (size_t)row * K + k0 + lsl * 8;
            u16* dstA = &lA[(size_t)(wave * 64 + i * 256) * 8];  // wave-uniform
            u16* dstW = &lW[(size_t)(wave * 64 + i * 256) * 8];
            __builtin_amdgcn_global_load_lds(
                (const __attribute__((address_space(1))) void*)(gA + go),
                (__attribute__((address_space(3))) void*)dstA, 16, 0, 0);
            __builtin_amdgcn_global_load_lds(
                (const __attribute__((address_space(1))) void*)(gW + go),
                (__attribute__((address_space(3))) void*)dstW, 16, 0, 0);
        }
        __syncthreads();   // drains vmcnt + orders LDS

        short8 ah[4], bh[4];
        #pragma unroll
        for (int m = 0; m < 4; m++) {
            const int ra = wr + m*16 + mrow;
            const int ps = ls ^ ((ra >> 1) & 3);
            ah[m] = *(const short8*)&lA[ra*32 + ps*8];
        }
        #pragma unroll
        for (int n = 0; n < 4; n++) {
            const int rb = wc + n*16 + mrow;
            const int ps = ls ^ ((rb >> 1) & 3);
            bh[n] = *(const short8*)&lW[rb*32 + ps*8];
        }

        #pragma unroll
        for (int m = 0; m < 4; m++)
            #pragma unroll
            for (int n = 0; n < 4; n++)
                acc[m][n] = __builtin_amdgcn_mfma_f32_16x16x32_bf16(ah[m], bh[n], acc[m][n], 0, 0, 0);
        __syncthreads();
    }

    // epilogue: C/D layout col=lane&15, row=(lane>>4)*4+r
    const int lrow = (lane >> 4) * 4;
    const int lcol = lane & 15;
    float bias_n[4];
    #pragma unroll
    for (int n = 0; n < 4; n++) bias_n[n] = bias[bn0 + wc + n*16 + lcol];

    #pragma unroll
    for (int m = 0; m < 4; m++) {
        #pragma unroll
        for (int n = 0; n < 4; n++) {
            const int col = bn0 + wc + n*16 + lcol;
            #pragma unroll
            for (int r = 0; r < 4; r++) {
                const int row = bm0 + wr + m*16 + lrow + r;
                float v = acc[m][n][r] + bias_n[n];
                if (EPI == 2) {
                    v = gelu_exact(v);
                    outh[(size_t)row * N + col] = f2bf(v);
                } else {
                    outf[(size_t)row * N + col] = v;
                }
            }
        }
    }
}

// ---------------------------------------------------------------------------
extern "C" void kernel_launch(void* const* d_in, const int* in_sizes, int n_in,
                              void* d_out, int out_size, void* d_ws, size_t ws_size,
                              hipStream_t stream)
{
    const float* x      = (const float*)d_in[0];
    const float* ln1_w  = (const float*)d_in[1];
    const float* ln1_b  = (const float*)d_in[2];
    // d_in[3..7]: state_flow/injection/readout/gate_w/gate_b — state_update
    // is identically zero (h0 = 0, update multiplicative in h) -> unused.
    const float* mlp_w1 = (const float*)d_in[8];
    const float* mlp_b1 = (const float*)d_in[9];
    const float* mlp_w2 = (const float*)d_in[10];
    const float* mlp_b2 = (const float*)d_in[11];
    const float* ln2_w  = (const float*)d_in[12];
    const float* ln2_b  = (const float*)d_in[13];
    float* out = (float*)d_out;

    const size_t MD = (size_t)M_ * D_;   // 33.55M
    const size_t HD = (size_t)H_ * D_;   // 4.19M

    // workspace: xcb [M,D] bf16 | w1b [H,D] bf16 | w2b [D,H] bf16 | hb [MC,H] bf16
    u16* xcb = (u16*)d_ws;
    u16* w1b = xcb + MD;
    u16* w2b = w1b + HD;
    u16* hb  = w2b + HD;

    const size_t base_bytes = (MD + 2 * HD) * 2;
    int MC = M_;                                  // prefer one chunk
    while (MC > 1024 && base_bytes + (size_t)MC * H_ * 2 > ws_size) MC >>= 1;

    // weight casts (fp32 -> bf16)
    cast_bf16_kernel<<<2048, 256, 0, stream>>>(mlp_w1, w1b, (int)(HD / 4));
    cast_bf16_kernel<<<2048, 256, 0, stream>>>(mlp_w2, w2b, (int)(HD / 4));

    // x1 = LN1(x), emitted directly as bf16 (only consumer is MLP1)
    ln_kernel<true, false><<<M_, 256, 0, stream>>>(x, ln1_w, ln1_b, xcb);

    // MLP: h = gelu(x1@W1^T+b1) [bf16], x3 = h@W2^T+b2 -> d_out (fp32)
    for (int c = 0; c < M_ / MC; c++) {
        gemm_b16<2, 5><<<dim3(H_/128, MC/128), 256, 0, stream>>>(
            xcb + (size_t)c * MC * D_, w1b, mlp_b1, nullptr, hb, H_, D_);
        gemm_b16<1, 3><<<dim3(D_/128, MC/128), 256, 0, stream>>>(
            hb, w2b, mlp_b2, out + (size_t)c * MC * D_, nullptr, D_, H_);
    }

    // out = x3 + LN2(x3), in place on d_out (every element written above)
    ln_kernel<false, true><<<M_, 256, 0, stream>>>(out, ln2_w, ln2_b, out);
}

// Round 7
// 1095.327 us; speedup vs baseline: 8.9574x; 1.0427x over previous
//
#include <hip/hip_runtime.h>
#include <math.h>

#define B_ 32
#define T_ 1024
#define D_ 1024
#define S_ 128
#define H_ 4096
#define M_ (B_*T_)          // 32768 rows
#define LN_EPS 1e-5f

typedef unsigned short u16;
typedef unsigned int   u32;
typedef short short8 __attribute__((ext_vector_type(8)));
typedef float f32x4  __attribute__((ext_vector_type(4)));

// bf16 round-to-nearest-even
__device__ __forceinline__ u16 f2bf(float x) {
    u32 u = __float_as_uint(x);
    u += 0x7FFFu + ((u >> 16) & 1u);
    return (u16)(u >> 16);
}

// ---------------------------------------------------------------------------
// NOTE: the reference's state_update is identically ZERO for all inputs:
// h0 = 0 and h_new = (1-g)*h + g*(h@flow^T) is multiplicative in h, so
// h == 0 for all t and ys == 0. The block reduces to
//   x1 = LN1(x); h = gelu(x1@W1^T+b1); x3 = h@W2^T+b2; out = x3 + LN2(x3).
// ---------------------------------------------------------------------------

// ---------------------------------------------------------------------------
// LayerNorm over last dim (D=1024). One block (256 thr) per row.
// OUT_BF16: write ushort4 bf16 (MLP1 input). ADD_INPUT: out = x + LN(x)*w+b,
// may run in place (x aliases outp) -> no __restrict__ on x/outp.
// ---------------------------------------------------------------------------
template<bool OUT_BF16, bool ADD_INPUT>
__global__ __launch_bounds__(256) void ln_kernel(const float* x,
                                                 const float* __restrict__ w,
                                                 const float* __restrict__ b,
                                                 void* outp)
{
    const int row = blockIdx.x;
    const int tid = threadIdx.x;
    const float4* xr = (const float4*)(x + (size_t)row * D_);
    float4 v = xr[tid];

    float s  = v.x + v.y + v.z + v.w;
    float ss = v.x*v.x + v.y*v.y + v.z*v.z + v.w*v.w;
    #pragma unroll
    for (int off = 32; off; off >>= 1) {
        s  += __shfl_down(s,  off);
        ss += __shfl_down(ss, off);
    }
    __shared__ float redS[4], redS2[4];
    __shared__ float mu_s, rstd_s;
    const int wave = tid >> 6;
    if ((tid & 63) == 0) { redS[wave] = s; redS2[wave] = ss; }
    __syncthreads();
    if (tid == 0) {
        float s0 = redS[0]+redS[1]+redS[2]+redS[3];
        float s1 = redS2[0]+redS2[1]+redS2[2]+redS2[3];
        float mu = s0 * (1.0f / D_);
        float var = s1 * (1.0f / D_) - mu * mu;
        mu_s = mu;
        rstd_s = rsqrtf(var + LN_EPS);
    }
    __syncthreads();
    const float mu = mu_s, rstd = rstd_s;

    float4 wv = ((const float4*)w)[tid];
    float4 bv = ((const float4*)b)[tid];
    float4 o;
    o.x = (v.x - mu) * rstd * wv.x + bv.x;
    o.y = (v.y - mu) * rstd * wv.y + bv.y;
    o.z = (v.z - mu) * rstd * wv.z + bv.z;
    o.w = (v.w - mu) * rstd * wv.w + bv.w;
    if (ADD_INPUT) { o.x += v.x; o.y += v.y; o.z += v.z; o.w += v.w; }

    if (OUT_BF16) {
        ushort4 h;
        h.x = f2bf(o.x); h.y = f2bf(o.y); h.z = f2bf(o.z); h.w = f2bf(o.w);
        ((ushort4*)((u16*)outp + (size_t)row * D_))[tid] = h;
    } else {
        ((float4*)((float*)outp + (size_t)row * D_))[tid] = o;
    }
}

// ---------------------------------------------------------------------------
// fp32 -> bf16 cast (weights), float4-vectorized.
// ---------------------------------------------------------------------------
__global__ __launch_bounds__(256) void cast_bf16_kernel(const float* __restrict__ in,
                                                        u16* __restrict__ out, int n4)
{
    for (int i = blockIdx.x * blockDim.x + threadIdx.x; i < n4;
         i += gridDim.x * blockDim.x) {
        float4 v = ((const float4*)in)[i];
        ushort4 h;
        h.x = f2bf(v.x); h.y = f2bf(v.y); h.z = f2bf(v.z); h.w = f2bf(v.w);
        ((ushort4*)out)[i] = h;
    }
}

// ---------------------------------------------------------------------------
// gelu, tanh-form: x*sigmoid(1.5957691*x*(1+0.044715 x^2)).
// |err vs exact erf-gelu| <= ~1e-3, below the bf16 rounding of h and far
// below the 0.0625 validated margin. __expf = v_exp_f32 (1 transcendental);
// rcp via __builtin_amdgcn_rcpf. Saturates correctly at +/-inf, branch-free.
// ~7 VALU vs ~25-30 for erff: the MLP1 epilogue was 69% VALUBusy.
// ---------------------------------------------------------------------------
__device__ __forceinline__ float gelu_fast(float v) {
    float u2 = 1.5957691216f * v * fmaf(0.044715f, v * v, 1.0f);
    return v * __builtin_amdgcn_rcpf(1.0f + __expf(-u2));
}

// ---------------------------------------------------------------------------
// Pure-bf16 MFMA GEMM (NT), m97 structure: 128x128 tile, BK=32, 4 waves,
// global_load_lds 16B staging, linear LDS dest + inverse-swizzled global src,
// swizzled ds_read (involution ps = ls ^ ((row>>1)&3)) -> 0 bank conflicts.
// XCD-aware block swizzle (nwg % 8 == 0 at all call sites; gx = 1<<LGX).
//   EPI 2: v = gelu(acc + bias); write bf16 outh          [MLP1]
//   EPI 1: v = acc + bias;       write fp32 outf          [MLP2]
// ---------------------------------------------------------------------------
template<int EPI, int LGX>
__global__ __launch_bounds__(256) void gemm_b16(const u16* __restrict__ A,
                                                const u16* __restrict__ W,
                                                const float* __restrict__ bias,
                                                float* outf, u16* outh,
                                                int N, int K)
{
    __shared__ u16 lA[128*32], lW[128*32];

    const int tid  = threadIdx.x;
    const int wave = tid >> 6;
    const int lane = tid & 63;

    // XCD swizzle: consecutive swizzled ids land on one XCD -> L2 panel reuse
    const int nwg = gridDim.x * gridDim.y;
    int bid = blockIdx.y * gridDim.x + blockIdx.x;
    bid = (bid & 7) * (nwg >> 3) + (bid >> 3);
    const int bn0 = (bid & ((1 << LGX) - 1)) * 128;
    const int bm0 = (bid >> LGX) * 128;

    const int wr = (wave >> 1) * 64;
    const int wc = (wave & 1) * 64;
    const int mrow = lane & 15;
    const int ls   = lane >> 4;        // logical 16B k-slot 0..3

    f32x4 acc[4][4];
    #pragma unroll
    for (int m = 0; m < 4; m++)
        #pragma unroll
        for (int n = 0; n < 4; n++)
            #pragma unroll
            for (int r = 0; r < 4; r++) acc[m][n][r] = 0.f;

    const u16* gA = A + (size_t)bm0 * K;
    const u16* gW = W + (size_t)bn0 * K;

    for (int k0 = 0; k0 < K; k0 += 32) {
        #pragma unroll
        for (int i = 0; i < 2; i++) {
            const int seg  = tid + i * 256;          // 0..511
            const int row  = seg >> 2;
            const int psl  = seg & 3;                // physical LDS slot
            const int lsl  = psl ^ ((row >> 1) & 3); // logical k-slot fetched
            const size_t go = (size_t)row * K + k0 + lsl * 8;
            u16* dstA = &lA[(size_t)(wave * 64 + i * 256) * 8];  // wave-uniform
            u16* dstW = &lW[(size_t)(wave * 64 + i * 256) * 8];
            __builtin_amdgcn_global_load_lds(
                (const __attribute__((address_space(1))) void*)(gA + go),
                (__attribute__((address_space(3))) void*)dstA, 16, 0, 0);
            __builtin_amdgcn_global_load_lds(
                (const __attribute__((address_space(1))) void*)(gW + go),
                (__attribute__((address_space(3))) void*)dstW, 16, 0, 0);
        }
        __syncthreads();   // drains vmcnt + orders LDS

        short8 ah[4], bh[4];
        #pragma unroll
        for (int m = 0; m < 4; m++) {
            const int ra = wr + m*16 + mrow;
            const int ps = ls ^ ((ra >> 1) & 3);
            ah[m] = *(const short8*)&lA[ra*32 + ps*8];
        }
        #pragma unroll
        for (int n = 0; n < 4; n++) {
            const int rb = wc + n*16 + mrow;
            const int ps = ls ^ ((rb >> 1) & 3);
            bh[n] = *(const short8*)&lW[rb*32 + ps*8];
        }

        #pragma unroll
        for (int m = 0; m < 4; m++)
            #pragma unroll
            for (int n = 0; n < 4; n++)
                acc[m][n] = __builtin_amdgcn_mfma_f32_16x16x32_bf16(ah[m], bh[n], acc[m][n], 0, 0, 0);
        __syncthreads();
    }

    // epilogue: C/D layout col=lane&15, row=(lane>>4)*4+r
    const int lrow = (lane >> 4) * 4;
    const int lcol = lane & 15;
    float bias_n[4];
    #pragma unroll
    for (int n = 0; n < 4; n++) bias_n[n] = bias[bn0 + wc + n*16 + lcol];

    #pragma unroll
    for (int m = 0; m < 4; m++) {
        #pragma unroll
        for (int n = 0; n < 4; n++) {
            const int col = bn0 + wc + n*16 + lcol;
            #pragma unroll
            for (int r = 0; r < 4; r++) {
                const int row = bm0 + wr + m*16 + lrow + r;
                float v = acc[m][n][r] + bias_n[n];
                if (EPI == 2) {
                    v = gelu_fast(v);
                    outh[(size_t)row * N + col] = f2bf(v);
                } else {
                    outf[(size_t)row * N + col] = v;
                }
            }
        }
    }
}

// ---------------------------------------------------------------------------
extern "C" void kernel_launch(void* const* d_in, const int* in_sizes, int n_in,
                              void* d_out, int out_size, void* d_ws, size_t ws_size,
                              hipStream_t stream)
{
    const float* x      = (const float*)d_in[0];
    const float* ln1_w  = (const float*)d_in[1];
    const float* ln1_b  = (const float*)d_in[2];
    // d_in[3..7]: state_flow/injection/readout/gate_w/gate_b — state_update
    // is identically zero (h0 = 0, update multiplicative in h) -> unused.
    const float* mlp_w1 = (const float*)d_in[8];
    const float* mlp_b1 = (const float*)d_in[9];
    const float* mlp_w2 = (const float*)d_in[10];
    const float* mlp_b2 = (const float*)d_in[11];
    const float* ln2_w  = (const float*)d_in[12];
    const float* ln2_b  = (const float*)d_in[13];
    float* out = (float*)d_out;

    const size_t MD = (size_t)M_ * D_;   // 33.55M
    const size_t HD = (size_t)H_ * D_;   // 4.19M

    // workspace: xcb [M,D] bf16 | w1b [H,D] bf16 | w2b [D,H] bf16 | hb [MC,H] bf16
    u16* xcb = (u16*)d_ws;
    u16* w1b = xcb + MD;
    u16* w2b = w1b + HD;
    u16* hb  = w2b + HD;

    const size_t base_bytes = (MD + 2 * HD) * 2;
    int MC = M_;                                  // prefer one chunk
    while (MC > 1024 && base_bytes + (size_t)MC * H_ * 2 > ws_size) MC >>= 1;

    // weight casts (fp32 -> bf16)
    cast_bf16_kernel<<<2048, 256, 0, stream>>>(mlp_w1, w1b, (int)(HD / 4));
    cast_bf16_kernel<<<2048, 256, 0, stream>>>(mlp_w2, w2b, (int)(HD / 4));

    // x1 = LN1(x), emitted directly as bf16 (only consumer is MLP1)
    ln_kernel<true, false><<<M_, 256, 0, stream>>>(x, ln1_w, ln1_b, xcb);

    // MLP: h = gelu(x1@W1^T+b1) [bf16], x3 = h@W2^T+b2 -> d_out (fp32)
    for (int c = 0; c < M_ / MC; c++) {
        gemm_b16<2, 5><<<dim3(H_/128, MC/128), 256, 0, stream>>>(
            xcb + (size_t)c * MC * D_, w1b, mlp_b1, nullptr, hb, H_, D_);
        gemm_b16<1, 3><<<dim3(D_/128, MC/128), 256, 0, stream>>>(
            hb, w2b, mlp_b2, out + (size_t)c * MC * D_, nullptr, D_, H_);
    }

    // out = x3 + LN2(x3), in place on d_out (every element written above)
    ln_kernel<false, true><<<M_, 256, 0, stream>>>(out, ln2_w, ln2_b, out);
}